// Round 1
// baseline (997.106 us; speedup 1.0000x reference)
//
#include <hip/hip_runtime.h>
#include <math.h>

#define DIM 128
#define CAP 128   // per-node CSR bucket capacity; degrees ~Poisson(16), P(deg>=128) ~ 0

// ---------------------------------------------------------------------------
// Kernel 1: fused 4-way projection  O_p = (h*norm) @ W_p + b_p   (fp32 VALU)
// 64-row tile per block, 256 threads, each thread computes 8x4 outputs.
// W staged in LDS in 32-row k-chunks, register-prefetched (double-buffered
// through VGPRs) so the global W load overlaps the FMA work of the previous
// chunk. sW padded to 132 so float4 staging stores cover all 32 banks.
// LDS = 64*132*4 + 32*132*4 = 50.7 KB -> 3 blocks/CU.
// ---------------------------------------------------------------------------
__global__ __launch_bounds__(256) void proj4_kernel(
    const float* __restrict__ h, const float* __restrict__ norm,
    const float* __restrict__ W0, const float* __restrict__ b0,
    const float* __restrict__ W1, const float* __restrict__ b1,
    const float* __restrict__ W2, const float* __restrict__ b2,
    const float* __restrict__ W3, const float* __restrict__ b3,
    float* __restrict__ O0, float* __restrict__ O1,
    float* __restrict__ O2, float* __restrict__ O3, int N)
{
    __shared__ float sA[64][132];   // 64x128 hn tile, padded
    __shared__ float sW[32][132];   // 32-row chunk of W, padded

    const int tid = threadIdx.x;
    const int rowBase = blockIdx.x * 64;

    // stage hn = h * norm tile (coalesced)
    for (int i = tid; i < 64 * DIM; i += 256) {
        int r = i >> 7, c = i & 127;
        int gr = rowBase + r;
        float v = 0.0f;
        if (gr < N) v = h[(size_t)gr * DIM + c] * norm[gr];
        sA[r][c] = v;
    }
    // (first __syncthreads in the kc loop covers this staging)

    const float* Ws[4] = {W0, W1, W2, W3};
    const float* bs[4] = {b0, b1, b2, b3};
    float* Os[4] = {O0, O1, O2, O3};

    const int c0 = (tid & 31) * 4;   // 4 output cols
    const int r0 = (tid >> 5) * 8;   // 8 output rows
    const int wrow = tid >> 3;        // 0..31   (W chunk row owned by thread)
    const int wcol = (tid & 7) * 16;  // 16 consecutive floats per thread

    for (int p = 0; p < 4; ++p) {
        const float* W = Ws[p];

        // prefetch chunk 0 of this projection into registers
        float4 pre0, pre1, pre2, pre3;
        {
            const float* Wp = W + (size_t)wrow * DIM + wcol;
            pre0 = *(const float4*)&Wp[0];
            pre1 = *(const float4*)&Wp[4];
            pre2 = *(const float4*)&Wp[8];
            pre3 = *(const float4*)&Wp[12];
        }

        float acc[8][4];
        #pragma unroll
        for (int i = 0; i < 8; ++i) {
            #pragma unroll
            for (int j = 0; j < 4; ++j) acc[i][j] = 0.0f;
        }

        for (int kc = 0; kc < DIM; kc += 32) {
            __syncthreads();   // previous chunk's readers done
            *(float4*)&sW[wrow][wcol]      = pre0;
            *(float4*)&sW[wrow][wcol + 4]  = pre1;
            *(float4*)&sW[wrow][wcol + 8]  = pre2;
            *(float4*)&sW[wrow][wcol + 12] = pre3;
            __syncthreads();

            // issue next chunk's global loads; latency hides under the FMAs
            if (kc + 32 < DIM) {
                const float* Wp = W + (size_t)(kc + 32 + wrow) * DIM + wcol;
                pre0 = *(const float4*)&Wp[0];
                pre1 = *(const float4*)&Wp[4];
                pre2 = *(const float4*)&Wp[8];
                pre3 = *(const float4*)&Wp[12];
            }

            #pragma unroll 4
            for (int k = 0; k < 32; k += 4) {
                float4 w[4];
                #pragma unroll
                for (int kk = 0; kk < 4; ++kk)
                    w[kk] = *(const float4*)&sW[k + kk][c0];
                #pragma unroll
                for (int i = 0; i < 8; ++i) {
                    float4 a = *(const float4*)&sA[r0 + i][kc + k];
                    acc[i][0] += a.x * w[0].x; acc[i][1] += a.x * w[0].y;
                    acc[i][2] += a.x * w[0].z; acc[i][3] += a.x * w[0].w;
                    acc[i][0] += a.y * w[1].x; acc[i][1] += a.y * w[1].y;
                    acc[i][2] += a.y * w[1].z; acc[i][3] += a.y * w[1].w;
                    acc[i][0] += a.z * w[2].x; acc[i][1] += a.z * w[2].y;
                    acc[i][2] += a.z * w[2].z; acc[i][3] += a.z * w[2].w;
                    acc[i][0] += a.w * w[3].x; acc[i][1] += a.w * w[3].y;
                    acc[i][2] += a.w * w[3].z; acc[i][3] += a.w * w[3].w;
                }
            }
        }

        float4 bias = *(const float4*)&bs[p][c0];
        float* O = Os[p];
        #pragma unroll
        for (int i = 0; i < 8; ++i) {
            int gr = rowBase + r0 + i;
            if (gr < N) {
                float4 o;
                o.x = acc[i][0] + bias.x;
                o.y = acc[i][1] + bias.y;
                o.z = acc[i][2] + bias.z;
                o.w = acc[i][3] + bias.w;
                *(float4*)&O[(size_t)gr * DIM + c0] = o;
            }
        }
    }
}

// ---------------------------------------------------------------------------
// Kernel 2: build dst-bucketed adjacency (count + scatter src into buckets)
// ---------------------------------------------------------------------------
__global__ void count_fill_kernel(const int* __restrict__ src,
                                  const int* __restrict__ dst,
                                  int* __restrict__ cnt,
                                  int* __restrict__ csr, int E)
{
    int e = blockIdx.x * blockDim.x + threadIdx.x;
    if (e < E) {
        int d = dst[e];
        int pos = atomicAdd(&cnt[d], 1);
        if (pos < CAP) csr[(size_t)d * CAP + pos] = src[e];
    }
}

// ---------------------------------------------------------------------------
// Kernel 3: per-node gated aggregation — wave-per-node version.
// 256-thread block = 4 waves = 4 nodes. Within a wave: lanes 0-31 handle
// even edges, lanes 32-63 odd edges; each lane owns 4 feature dims (float4
// gathers, 16 B/lane). No LDS, no barriers; halves combined via shfl_xor(32).
// ---------------------------------------------------------------------------
__global__ __launch_bounds__(256) void aggregate_kernel(
    const float* __restrict__ Ah, const float* __restrict__ Bh,
    const float* __restrict__ Dh, const float* __restrict__ Eh,
    const float* __restrict__ norm,
    const int* __restrict__ cnt, const int* __restrict__ csr,
    float* __restrict__ out, int N)
{
    const int lane = threadIdx.x & 63;
    const int wv   = threadIdx.x >> 6;
    const int n    = blockIdx.x * 4 + wv;
    if (n >= N) return;                    // no barriers in kernel: safe

    const int half = lane >> 5;            // 0 = even edge, 1 = odd edge
    const int c0   = (lane & 31) * 4;      // 4 dims per lane

    int deg = cnt[n];
    if (deg > CAP) deg = CAP;

    // Eh row: both halves load the same float4 -> broadcast
    const float4 eh = *(const float4*)&Eh[(size_t)n * DIM + c0];
    const int* crow = csr + (size_t)n * CAP;

    float nx = 0.f, ny = 0.f, nz = 0.f, nw = 0.f;
    float dx = 0.f, dy = 0.f, dz = 0.f, dw = 0.f;

    #pragma unroll 2
    for (int j = 0; j < deg; j += 2) {
        int jj = j + half;
        bool act = jj < deg;
        int s = crow[act ? jj : j];        // uniform within half-wave
        float4 dv = *(const float4*)&Dh[(size_t)s * DIM + c0];
        float4 bv = *(const float4*)&Bh[(size_t)s * DIM + c0];
        float sx = 1.0f / (1.0f + __expf(-(dv.x + eh.x)));
        float sy = 1.0f / (1.0f + __expf(-(dv.y + eh.y)));
        float sz = 1.0f / (1.0f + __expf(-(dv.z + eh.z)));
        float sw = 1.0f / (1.0f + __expf(-(dv.w + eh.w)));
        if (!act) { sx = 0.f; sy = 0.f; sz = 0.f; sw = 0.f; }
        nx += sx * bv.x; ny += sy * bv.y; nz += sz * bv.z; nw += sw * bv.w;
        dx += sx; dy += sy; dz += sz; dw += sw;
    }

    // combine even/odd halves across the lane^32 boundary
    nx += __shfl_xor(nx, 32); ny += __shfl_xor(ny, 32);
    nz += __shfl_xor(nz, 32); nw += __shfl_xor(nw, 32);
    dx += __shfl_xor(dx, 32); dy += __shfl_xor(dy, 32);
    dz += __shfl_xor(dz, 32); dw += __shfl_xor(dw, 32);

    if (half == 0) {
        float4 av = *(const float4*)&Ah[(size_t)n * DIM + c0];
        float nm = norm[n];
        float4 o;
        o.x = (av.x + nx / (dx + 1e-6f)) * nm;
        o.y = (av.y + ny / (dy + 1e-6f)) * nm;
        o.z = (av.z + nz / (dz + 1e-6f)) * nm;
        o.w = (av.w + nw / (dw + 1e-6f)) * nm;
        *(float4*)&out[(size_t)n * DIM + c0] = o;
    }
}

// ---------------------------------------------------------------------------
// Kernel 4: passthrough copy of e into the output buffer (re-poisoned each call)
// ---------------------------------------------------------------------------
__global__ void copy_e_kernel(const float4* __restrict__ in,
                              float4* __restrict__ out, int n4)
{
    int i = blockIdx.x * blockDim.x + threadIdx.x;
    int stride = gridDim.x * blockDim.x;
    for (; i < n4; i += stride) out[i] = in[i];
}

// ---------------------------------------------------------------------------
extern "C" void kernel_launch(void* const* d_in, const int* in_sizes, int n_in,
                              void* d_out, int out_size, void* d_ws, size_t ws_size,
                              hipStream_t stream)
{
    const float* h    = (const float*)d_in[0];
    const float* e    = (const float*)d_in[1];
    const float* norm = (const float*)d_in[2];
    const int*   src  = (const int*)d_in[3];
    const int*   dst  = (const int*)d_in[4];
    const float* WA = (const float*)d_in[5];
    const float* bA = (const float*)d_in[6];
    const float* WB = (const float*)d_in[7];
    const float* bB = (const float*)d_in[8];
    const float* WD = (const float*)d_in[9];
    const float* bD = (const float*)d_in[10];
    const float* WE = (const float*)d_in[11];
    const float* bE = (const float*)d_in[12];

    const int N = in_sizes[0] / DIM;   // 50000
    const int E = in_sizes[3];         // 800000

    float* out_h = (float*)d_out;
    float* out_e = out_h + (size_t)N * DIM;

    // workspace layout: Ah|Bh|Dh|Eh (4*N*D f32) | cnt (N i32) | csr (N*CAP i32)
    float* ws = (float*)d_ws;
    float* Ah = ws;
    float* Bh = Ah + (size_t)N * DIM;
    float* Dh = Bh + (size_t)N * DIM;
    float* Eh = Dh + (size_t)N * DIM;
    int* cnt  = (int*)(Eh + (size_t)N * DIM);
    int* csr  = cnt + N;

    hipMemsetAsync(cnt, 0, (size_t)N * sizeof(int), stream);

    count_fill_kernel<<<(E + 255) / 256, 256, 0, stream>>>(src, dst, cnt, csr, E);

    proj4_kernel<<<(N + 63) / 64, 256, 0, stream>>>(
        h, norm, WA, bA, WB, bB, WD, bD, WE, bE, Ah, Bh, Dh, Eh, N);

    aggregate_kernel<<<(N + 3) / 4, 256, 0, stream>>>(
        Ah, Bh, Dh, Eh, norm, cnt, csr, out_h, N);

    const int n4 = (E * DIM) / 4;
    copy_e_kernel<<<4096, 256, 0, stream>>>((const float4*)e, (float4*)out_e, n4);
}

// Round 2
// 929.642 us; speedup vs baseline: 1.0726x; 1.0726x over previous
//
#include <hip/hip_runtime.h>
#include <math.h>

#define DIM 128
#define CAP 128   // per-node CSR bucket capacity; degrees ~Poisson(16), P(deg>=128) ~ 0

typedef float __attribute__((ext_vector_type(4))) f4v;

// ---------------------------------------------------------------------------
// Kernel 1: fused 4-way projection  O_p = (h*norm) @ W_p + b_p   (fp32 VALU)
// 64-row tile per block, 256 threads, each thread computes 8x4 outputs.
// W staged in LDS in 32-row k-chunks, register-prefetched so the global W
// load overlaps the FMA work of the previous chunk.
// FUSED: carries ~25% of the e->out_e passthrough copy, 2 float4/thread per
// k-chunk (16 chunks). Nontemporal loads issue before the FMA loop, stores
// after it -> HBM latency hides under ~2048 cyc of FMA per wave.
// LDS = 64*132*4 + 32*132*4 = 50.7 KB -> 3 blocks/CU.
// ---------------------------------------------------------------------------
__global__ __launch_bounds__(256) void proj4_kernel(
    const float* __restrict__ h, const float* __restrict__ norm,
    const float* __restrict__ W0, const float* __restrict__ b0,
    const float* __restrict__ W1, const float* __restrict__ b1,
    const float* __restrict__ W2, const float* __restrict__ b2,
    const float* __restrict__ W3, const float* __restrict__ b3,
    float* __restrict__ O0, float* __restrict__ O1,
    float* __restrict__ O2, float* __restrict__ O3, int N,
    const f4v* __restrict__ e_in, f4v* __restrict__ e_out)
{
    __shared__ float sA[64][132];   // 64x128 hn tile, padded
    __shared__ float sW[32][132];   // 32-row chunk of W, padded

    const int tid = threadIdx.x;
    const int rowBase = blockIdx.x * 64;

    // stage hn = h * norm tile (coalesced)
    for (int i = tid; i < 64 * DIM; i += 256) {
        int r = i >> 7, c = i & 127;
        int gr = rowBase + r;
        float v = 0.0f;
        if (gr < N) v = h[(size_t)gr * DIM + c] * norm[gr];
        sA[r][c] = v;
    }
    // (first __syncthreads in the kc loop covers this staging)

    const float* Ws[4] = {W0, W1, W2, W3};
    const float* bs[4] = {b0, b1, b2, b3};
    float* Os[4] = {O0, O1, O2, O3};

    const int c0 = (tid & 31) * 4;   // 4 output cols
    const int r0 = (tid >> 5) * 8;   // 8 output rows
    const int wrow = tid >> 3;        // 0..31   (W chunk row owned by thread)
    const int wcol = (tid & 7) * 16;  // 16 consecutive floats per thread

    int t = 0;  // chunk counter 0..15 for the fused copy slice

    for (int p = 0; p < 4; ++p) {
        const float* W = Ws[p];

        // prefetch chunk 0 of this projection into registers
        float4 pre0, pre1, pre2, pre3;
        {
            const float* Wp = W + (size_t)wrow * DIM + wcol;
            pre0 = *(const float4*)&Wp[0];
            pre1 = *(const float4*)&Wp[4];
            pre2 = *(const float4*)&Wp[8];
            pre3 = *(const float4*)&Wp[12];
        }

        float acc[8][4];
        #pragma unroll
        for (int i = 0; i < 8; ++i) {
            #pragma unroll
            for (int j = 0; j < 4; ++j) acc[i][j] = 0.0f;
        }

        for (int kc = 0; kc < DIM; kc += 32) {
            __syncthreads();   // previous chunk's readers done
            *(float4*)&sW[wrow][wcol]      = pre0;
            *(float4*)&sW[wrow][wcol + 4]  = pre1;
            *(float4*)&sW[wrow][wcol + 8]  = pre2;
            *(float4*)&sW[wrow][wcol + 12] = pre3;
            __syncthreads();

            // issue next chunk's global W loads; latency hides under the FMAs
            if (kc + 32 < DIM) {
                const float* Wp = W + (size_t)(kc + 32 + wrow) * DIM + wcol;
                pre0 = *(const float4*)&Wp[0];
                pre1 = *(const float4*)&Wp[4];
                pre2 = *(const float4*)&Wp[8];
                pre3 = *(const float4*)&Wp[12];
            }

            // fused e-copy: issue 2 nontemporal loads now, store after FMAs
            const size_t cb = ((size_t)t * gridDim.x + blockIdx.x) * 512 + tid;
            f4v cv0 = __builtin_nontemporal_load(e_in + cb);
            f4v cv1 = __builtin_nontemporal_load(e_in + cb + 256);

            #pragma unroll 4
            for (int k = 0; k < 32; k += 4) {
                float4 w[4];
                #pragma unroll
                for (int kk = 0; kk < 4; ++kk)
                    w[kk] = *(const float4*)&sW[k + kk][c0];
                #pragma unroll
                for (int i = 0; i < 8; ++i) {
                    float4 a = *(const float4*)&sA[r0 + i][kc + k];
                    acc[i][0] += a.x * w[0].x; acc[i][1] += a.x * w[0].y;
                    acc[i][2] += a.x * w[0].z; acc[i][3] += a.x * w[0].w;
                    acc[i][0] += a.y * w[1].x; acc[i][1] += a.y * w[1].y;
                    acc[i][2] += a.y * w[1].z; acc[i][3] += a.y * w[1].w;
                    acc[i][0] += a.z * w[2].x; acc[i][1] += a.z * w[2].y;
                    acc[i][2] += a.z * w[2].z; acc[i][3] += a.z * w[2].w;
                    acc[i][0] += a.w * w[3].x; acc[i][1] += a.w * w[3].y;
                    acc[i][2] += a.w * w[3].z; acc[i][3] += a.w * w[3].w;
                }
            }

            __builtin_nontemporal_store(cv0, e_out + cb);
            __builtin_nontemporal_store(cv1, e_out + cb + 256);
            ++t;
        }

        float4 bias = *(const float4*)&bs[p][c0];
        float* O = Os[p];
        #pragma unroll
        for (int i = 0; i < 8; ++i) {
            int gr = rowBase + r0 + i;
            if (gr < N) {
                float4 o;
                o.x = acc[i][0] + bias.x;
                o.y = acc[i][1] + bias.y;
                o.z = acc[i][2] + bias.z;
                o.w = acc[i][3] + bias.w;
                *(float4*)&O[(size_t)gr * DIM + c0] = o;
            }
        }
    }
}

// ---------------------------------------------------------------------------
// Kernel 2: build dst-bucketed adjacency (count + scatter src into buckets)
// ---------------------------------------------------------------------------
__global__ void count_fill_kernel(const int* __restrict__ src,
                                  const int* __restrict__ dst,
                                  int* __restrict__ cnt,
                                  int* __restrict__ csr, int E)
{
    int e = blockIdx.x * blockDim.x + threadIdx.x;
    if (e < E) {
        int d = dst[e];
        int pos = atomicAdd(&cnt[d], 1);
        if (pos < CAP) csr[(size_t)d * CAP + pos] = src[e];
    }
}

// ---------------------------------------------------------------------------
// Kernel 3: per-node gated aggregation — wave-per-node. 256-thread block =
// 4 waves = 4 nodes. Lanes 0-31 even edges, 32-63 odd edges; each lane owns
// 4 dims (float4 gathers). Halves combined via shfl_xor(32). No LDS/barriers.
// FUSED: carries ~75% of the e->out_e copy (6 float4/thread, nontemporal);
// loads issued at entry, stores at exit -> rides HBM idle during the
// latency-bound gather loop.
// ---------------------------------------------------------------------------
__global__ __launch_bounds__(256) void aggregate_kernel(
    const float* __restrict__ Ah, const float* __restrict__ Bh,
    const float* __restrict__ Dh, const float* __restrict__ Eh,
    const float* __restrict__ norm,
    const int* __restrict__ cnt, const int* __restrict__ csr,
    float* __restrict__ out, int N,
    const f4v* __restrict__ e_in, f4v* __restrict__ e_out,
    int copyBase, int n4)
{
    // ---- fused copy: issue loads first ----
    const size_t cb = (size_t)copyBase + (size_t)blockIdx.x * 1536 + threadIdx.x;
    f4v c0v, c1v, c2v, c3v, c4v, c5v;
    const bool g0 = cb            < (size_t)n4;
    const bool g1 = cb + 256      < (size_t)n4;
    const bool g2 = cb + 512      < (size_t)n4;
    const bool g3 = cb + 768      < (size_t)n4;
    const bool g4 = cb + 1024     < (size_t)n4;
    const bool g5 = cb + 1280     < (size_t)n4;
    if (g0) c0v = __builtin_nontemporal_load(e_in + cb);
    if (g1) c1v = __builtin_nontemporal_load(e_in + cb + 256);
    if (g2) c2v = __builtin_nontemporal_load(e_in + cb + 512);
    if (g3) c3v = __builtin_nontemporal_load(e_in + cb + 768);
    if (g4) c4v = __builtin_nontemporal_load(e_in + cb + 1024);
    if (g5) c5v = __builtin_nontemporal_load(e_in + cb + 1280);

    const int lane = threadIdx.x & 63;
    const int wv   = threadIdx.x >> 6;
    const int n    = blockIdx.x * 4 + wv;

    if (n < N) {
        const int half = lane >> 5;            // 0 = even edge, 1 = odd edge
        const int c0   = (lane & 31) * 4;      // 4 dims per lane

        int deg = cnt[n];
        if (deg > CAP) deg = CAP;

        const float4 eh = *(const float4*)&Eh[(size_t)n * DIM + c0];
        const int* crow = csr + (size_t)n * CAP;

        float nx = 0.f, ny = 0.f, nz = 0.f, nw = 0.f;
        float dx = 0.f, dy = 0.f, dz = 0.f, dw = 0.f;

        #pragma unroll 4
        for (int j = 0; j < deg; j += 2) {
            int jj = j + half;
            bool act = jj < deg;
            int s = crow[act ? jj : j];        // uniform within half-wave
            float4 dv = *(const float4*)&Dh[(size_t)s * DIM + c0];
            float4 bv = *(const float4*)&Bh[(size_t)s * DIM + c0];
            float sx = 1.0f / (1.0f + __expf(-(dv.x + eh.x)));
            float sy = 1.0f / (1.0f + __expf(-(dv.y + eh.y)));
            float sz = 1.0f / (1.0f + __expf(-(dv.z + eh.z)));
            float sw = 1.0f / (1.0f + __expf(-(dv.w + eh.w)));
            if (!act) { sx = 0.f; sy = 0.f; sz = 0.f; sw = 0.f; }
            nx += sx * bv.x; ny += sy * bv.y; nz += sz * bv.z; nw += sw * bv.w;
            dx += sx; dy += sy; dz += sz; dw += sw;
        }

        // combine even/odd halves across the lane^32 boundary
        nx += __shfl_xor(nx, 32); ny += __shfl_xor(ny, 32);
        nz += __shfl_xor(nz, 32); nw += __shfl_xor(nw, 32);
        dx += __shfl_xor(dx, 32); dy += __shfl_xor(dy, 32);
        dz += __shfl_xor(dz, 32); dw += __shfl_xor(dw, 32);

        if (half == 0) {
            float4 av = *(const float4*)&Ah[(size_t)n * DIM + c0];
            float nm = norm[n];
            float4 o;
            o.x = (av.x + nx / (dx + 1e-6f)) * nm;
            o.y = (av.y + ny / (dy + 1e-6f)) * nm;
            o.z = (av.z + nz / (dz + 1e-6f)) * nm;
            o.w = (av.w + nw / (dw + 1e-6f)) * nm;
            *(float4*)&out[(size_t)n * DIM + c0] = o;
        }
    }

    // ---- fused copy: stores at exit ----
    if (g0) __builtin_nontemporal_store(c0v, e_out + cb);
    if (g1) __builtin_nontemporal_store(c1v, e_out + cb + 256);
    if (g2) __builtin_nontemporal_store(c2v, e_out + cb + 512);
    if (g3) __builtin_nontemporal_store(c3v, e_out + cb + 768);
    if (g4) __builtin_nontemporal_store(c4v, e_out + cb + 1024);
    if (g5) __builtin_nontemporal_store(c5v, e_out + cb + 1280);
}

// ---------------------------------------------------------------------------
extern "C" void kernel_launch(void* const* d_in, const int* in_sizes, int n_in,
                              void* d_out, int out_size, void* d_ws, size_t ws_size,
                              hipStream_t stream)
{
    const float* h    = (const float*)d_in[0];
    const float* e    = (const float*)d_in[1];
    const float* norm = (const float*)d_in[2];
    const int*   src  = (const int*)d_in[3];
    const int*   dst  = (const int*)d_in[4];
    const float* WA = (const float*)d_in[5];
    const float* bA = (const float*)d_in[6];
    const float* WB = (const float*)d_in[7];
    const float* bB = (const float*)d_in[8];
    const float* WD = (const float*)d_in[9];
    const float* bD = (const float*)d_in[10];
    const float* WE = (const float*)d_in[11];
    const float* bE = (const float*)d_in[12];

    const int N = in_sizes[0] / DIM;   // 50000
    const int E = in_sizes[3];         // 800000

    float* out_h = (float*)d_out;
    float* out_e = out_h + (size_t)N * DIM;

    // workspace layout: Ah|Bh|Dh|Eh (4*N*D f32) | cnt (N i32) | csr (N*CAP i32)
    float* ws = (float*)d_ws;
    float* Ah = ws;
    float* Bh = Ah + (size_t)N * DIM;
    float* Dh = Bh + (size_t)N * DIM;
    float* Eh = Dh + (size_t)N * DIM;
    int* cnt  = (int*)(Eh + (size_t)N * DIM);
    int* csr  = cnt + N;

    hipMemsetAsync(cnt, 0, (size_t)N * sizeof(int), stream);

    count_fill_kernel<<<(E + 255) / 256, 256, 0, stream>>>(src, dst, cnt, csr, E);

    const int n4 = (E * DIM) / 4;            // 25.6M float4
    const int gridP = (N + 63) / 64;         // 782
    const int Q = gridP * 16 * 512;          // proj4's copy share (~25%)

    proj4_kernel<<<gridP, 256, 0, stream>>>(
        h, norm, WA, bA, WB, bB, WD, bD, WE, bE, Ah, Bh, Dh, Eh, N,
        (const f4v*)e, (f4v*)out_e);

    aggregate_kernel<<<(N + 3) / 4, 256, 0, stream>>>(
        Ah, Bh, Dh, Eh, norm, cnt, csr, out_h, N,
        (const f4v*)e, (f4v*)out_e, Q, n4);
}

// Round 4
// 916.435 us; speedup vs baseline: 1.0880x; 1.0144x over previous
//
#include <hip/hip_runtime.h>
#include <math.h>

#define DIM 128
#define CAP 128   // per-node CSR bucket capacity; degrees ~Poisson(16), P(deg>=128) ~ 0

typedef float __attribute__((ext_vector_type(4))) f4v;

// ---------------------------------------------------------------------------
// Kernel 1: fused [count_fill prologue] + 4-way projection + 37.5% of e-copy.
//   - count prologue: 4 edges/thread, atomicAdd + scatter, fire-and-forget;
//     latency hides under the 16 GEMM k-chunks. Kernel boundary before
//     aggregate guarantees completion.
//   - GEMM: 64-row tile, 256 threads, 8x4 outputs/thread, W staged in LDS in
//     32-row chunks, register-prefetched (next chunk's global loads issued
//     before the FMA loop of the current chunk).
//   - copy: 3 nontemporal float4/thread per chunk (16 chunks) = gridP*12288
//     f4v total; loads before FMAs, stores after -> rides idle HBM.
// LDS = 64*132*4 + 32*132*4 = 50.7 KB -> 3 blocks/CU.
// ---------------------------------------------------------------------------
__global__ __launch_bounds__(256) void proj4_kernel(
    const float* __restrict__ h, const float* __restrict__ norm,
    const float* __restrict__ W0, const float* __restrict__ b0,
    const float* __restrict__ W1, const float* __restrict__ b1,
    const float* __restrict__ W2, const float* __restrict__ b2,
    const float* __restrict__ W3, const float* __restrict__ b3,
    float* __restrict__ O0, float* __restrict__ O1,
    float* __restrict__ O2, float* __restrict__ O3, int N,
    const int* __restrict__ src, const int* __restrict__ dst,
    int* __restrict__ cnt, int* __restrict__ csr, int E,
    const f4v* __restrict__ e_in, f4v* __restrict__ e_out)
{
    __shared__ float sA[64][132];   // 64x128 hn tile, padded
    __shared__ float sW[32][132];   // 32-row chunk of W, padded

    const int tid = threadIdx.x;
    const int rowBase = blockIdx.x * 64;

    // stage hn = h * norm tile (coalesced)
    for (int i = tid; i < 64 * DIM; i += 256) {
        int r = i >> 7, c = i & 127;
        int gr = rowBase + r;
        float v = 0.0f;
        if (gr < N) v = h[(size_t)gr * DIM + c] * norm[gr];
        sA[r][c] = v;
    }

    // ---- count_fill prologue: fire-and-forget, hides under the GEMM ----
    {
        const int ET = gridDim.x * 256;           // ~200K threads, 4 edges each
        for (int ee = blockIdx.x * 256 + tid; ee < E; ee += ET) {
            int d = dst[ee];
            int pos = atomicAdd(&cnt[d], 1);
            if (pos < CAP) csr[(size_t)d * CAP + pos] = src[ee];
        }
    }

    const float* Ws[4] = {W0, W1, W2, W3};
    const float* bs[4] = {b0, b1, b2, b3};
    float* Os[4] = {O0, O1, O2, O3};

    const int c0 = (tid & 31) * 4;   // 4 output cols
    const int r0 = (tid >> 5) * 8;   // 8 output rows
    const int wrow = tid >> 3;        // 0..31   (W chunk row owned by thread)
    const int wcol = (tid & 7) * 16;  // 16 consecutive floats per thread

    int t = 0;  // chunk counter 0..15 for the fused copy slice

    for (int p = 0; p < 4; ++p) {
        const float* W = Ws[p];

        // prefetch chunk 0 of this projection into registers
        float4 pre0, pre1, pre2, pre3;
        {
            const float* Wp = W + (size_t)wrow * DIM + wcol;
            pre0 = *(const float4*)&Wp[0];
            pre1 = *(const float4*)&Wp[4];
            pre2 = *(const float4*)&Wp[8];
            pre3 = *(const float4*)&Wp[12];
        }

        float acc[8][4];
        #pragma unroll
        for (int i = 0; i < 8; ++i) {
            #pragma unroll
            for (int j = 0; j < 4; ++j) acc[i][j] = 0.0f;
        }

        for (int kc = 0; kc < DIM; kc += 32) {
            __syncthreads();   // previous chunk's readers done (also covers sA staging)
            *(float4*)&sW[wrow][wcol]      = pre0;
            *(float4*)&sW[wrow][wcol + 4]  = pre1;
            *(float4*)&sW[wrow][wcol + 8]  = pre2;
            *(float4*)&sW[wrow][wcol + 12] = pre3;
            __syncthreads();

            // issue next chunk's global W loads; latency hides under the FMAs
            if (kc + 32 < DIM) {
                const float* Wp = W + (size_t)(kc + 32 + wrow) * DIM + wcol;
                pre0 = *(const float4*)&Wp[0];
                pre1 = *(const float4*)&Wp[4];
                pre2 = *(const float4*)&Wp[8];
                pre3 = *(const float4*)&Wp[12];
            }

            // fused e-copy: 3 nontemporal loads now, stores after the FMAs
            const size_t cb = ((size_t)t * gridDim.x + blockIdx.x) * 768 + tid;
            f4v cv0 = __builtin_nontemporal_load(e_in + cb);
            f4v cv1 = __builtin_nontemporal_load(e_in + cb + 256);
            f4v cv2 = __builtin_nontemporal_load(e_in + cb + 512);

            #pragma unroll 4
            for (int k = 0; k < 32; k += 4) {
                float4 w[4];
                #pragma unroll
                for (int kk = 0; kk < 4; ++kk)
                    w[kk] = *(const float4*)&sW[k + kk][c0];
                #pragma unroll
                for (int i = 0; i < 8; ++i) {
                    float4 a = *(const float4*)&sA[r0 + i][kc + k];
                    acc[i][0] += a.x * w[0].x; acc[i][1] += a.x * w[0].y;
                    acc[i][2] += a.x * w[0].z; acc[i][3] += a.x * w[0].w;
                    acc[i][0] += a.y * w[1].x; acc[i][1] += a.y * w[1].y;
                    acc[i][2] += a.y * w[1].z; acc[i][3] += a.y * w[1].w;
                    acc[i][0] += a.z * w[2].x; acc[i][1] += a.z * w[2].y;
                    acc[i][2] += a.z * w[2].z; acc[i][3] += a.z * w[2].w;
                    acc[i][0] += a.w * w[3].x; acc[i][1] += a.w * w[3].y;
                    acc[i][2] += a.w * w[3].z; acc[i][3] += a.w * w[3].w;
                }
            }

            __builtin_nontemporal_store(cv0, e_out + cb);
            __builtin_nontemporal_store(cv1, e_out + cb + 256);
            __builtin_nontemporal_store(cv2, e_out + cb + 512);
            ++t;
        }

        float4 bias = *(const float4*)&bs[p][c0];
        float* O = Os[p];
        #pragma unroll
        for (int i = 0; i < 8; ++i) {
            int gr = rowBase + r0 + i;
            if (gr < N) {
                float4 o;
                o.x = acc[i][0] + bias.x;
                o.y = acc[i][1] + bias.y;
                o.z = acc[i][2] + bias.z;
                o.w = acc[i][3] + bias.w;
                *(float4*)&O[(size_t)gr * DIM + c0] = o;   // cacheable: re-read by aggregate
            }
        }
    }
}

// ---------------------------------------------------------------------------
// Kernel 2: per-node gated aggregation — wave-per-node. 256-thread block =
// 4 waves = 4 nodes. Lanes 0-31 even edges, 32-63 odd edges; each lane owns
// 4 dims (float4 gathers). Halves combined via shfl_xor(32). No LDS/barriers.
// FUSED: carries 62.5% of the e-copy (5 float4/thread, nontemporal);
// loads at entry, stores at exit -> rides HBM idle during the gather loop.
// ---------------------------------------------------------------------------
__global__ __launch_bounds__(256) void aggregate_kernel(
    const float* __restrict__ Ah, const float* __restrict__ Bh,
    const float* __restrict__ Dh, const float* __restrict__ Eh,
    const float* __restrict__ norm,
    const int* __restrict__ cnt, const int* __restrict__ csr,
    float* __restrict__ out, int N,
    const f4v* __restrict__ e_in, f4v* __restrict__ e_out,
    int copyBase, int n4)
{
    // ---- fused copy: issue loads first ----
    const size_t cb = (size_t)copyBase + (size_t)blockIdx.x * 1280 + threadIdx.x;
    f4v c0v, c1v, c2v, c3v, c4v;
    const bool g0 = cb            < (size_t)n4;
    const bool g1 = cb + 256      < (size_t)n4;
    const bool g2 = cb + 512      < (size_t)n4;
    const bool g3 = cb + 768      < (size_t)n4;
    const bool g4 = cb + 1024     < (size_t)n4;
    if (g0) c0v = __builtin_nontemporal_load(e_in + cb);
    if (g1) c1v = __builtin_nontemporal_load(e_in + cb + 256);
    if (g2) c2v = __builtin_nontemporal_load(e_in + cb + 512);
    if (g3) c3v = __builtin_nontemporal_load(e_in + cb + 768);
    if (g4) c4v = __builtin_nontemporal_load(e_in + cb + 1024);

    const int lane = threadIdx.x & 63;
    const int wv   = threadIdx.x >> 6;
    const int n    = blockIdx.x * 4 + wv;

    if (n < N) {
        const int half = lane >> 5;            // 0 = even edge, 1 = odd edge
        const int c0   = (lane & 31) * 4;      // 4 dims per lane

        int deg = cnt[n];
        if (deg > CAP) deg = CAP;

        const float4 eh = *(const float4*)&Eh[(size_t)n * DIM + c0];
        const int* crow = csr + (size_t)n * CAP;

        float nx = 0.f, ny = 0.f, nz = 0.f, nw = 0.f;
        float dx = 0.f, dy = 0.f, dz = 0.f, dw = 0.f;

        #pragma unroll 4
        for (int j = 0; j < deg; j += 2) {
            int jj = j + half;
            bool act = jj < deg;
            int s = crow[act ? jj : j];        // uniform within half-wave
            float4 dv = *(const float4*)&Dh[(size_t)s * DIM + c0];
            float4 bv = *(const float4*)&Bh[(size_t)s * DIM + c0];
            float sx = 1.0f / (1.0f + __expf(-(dv.x + eh.x)));
            float sy = 1.0f / (1.0f + __expf(-(dv.y + eh.y)));
            float sz = 1.0f / (1.0f + __expf(-(dv.z + eh.z)));
            float sw = 1.0f / (1.0f + __expf(-(dv.w + eh.w)));
            if (!act) { sx = 0.f; sy = 0.f; sz = 0.f; sw = 0.f; }
            nx += sx * bv.x; ny += sy * bv.y; nz += sz * bv.z; nw += sw * bv.w;
            dx += sx; dy += sy; dz += sz; dw += sw;
        }

        // combine even/odd halves across the lane^32 boundary
        nx += __shfl_xor(nx, 32); ny += __shfl_xor(ny, 32);
        nz += __shfl_xor(nz, 32); nw += __shfl_xor(nw, 32);
        dx += __shfl_xor(dx, 32); dy += __shfl_xor(dy, 32);
        dz += __shfl_xor(dz, 32); dw += __shfl_xor(dw, 32);

        if (half == 0) {
            float4 av = *(const float4*)&Ah[(size_t)n * DIM + c0];
            float nm = norm[n];
            f4v o;
            o.x = (av.x + nx / (dx + 1e-6f)) * nm;
            o.y = (av.y + ny / (dy + 1e-6f)) * nm;
            o.z = (av.z + nz / (dz + 1e-6f)) * nm;
            o.w = (av.w + nw / (dw + 1e-6f)) * nm;
            __builtin_nontemporal_store(o, (f4v*)&out[(size_t)n * DIM + c0]);
        }
    }

    // ---- fused copy: stores at exit ----
    if (g0) __builtin_nontemporal_store(c0v, e_out + cb);
    if (g1) __builtin_nontemporal_store(c1v, e_out + cb + 256);
    if (g2) __builtin_nontemporal_store(c2v, e_out + cb + 512);
    if (g3) __builtin_nontemporal_store(c3v, e_out + cb + 768);
    if (g4) __builtin_nontemporal_store(c4v, e_out + cb + 1024);
}

// ---------------------------------------------------------------------------
extern "C" void kernel_launch(void* const* d_in, const int* in_sizes, int n_in,
                              void* d_out, int out_size, void* d_ws, size_t ws_size,
                              hipStream_t stream)
{
    const float* h    = (const float*)d_in[0];
    const float* e    = (const float*)d_in[1];
    const float* norm = (const float*)d_in[2];
    const int*   src  = (const int*)d_in[3];
    const int*   dst  = (const int*)d_in[4];
    const float* WA = (const float*)d_in[5];
    const float* bA = (const float*)d_in[6];
    const float* WB = (const float*)d_in[7];
    const float* bB = (const float*)d_in[8];
    const float* WD = (const float*)d_in[9];
    const float* bD = (const float*)d_in[10];
    const float* WE = (const float*)d_in[11];
    const float* bE = (const float*)d_in[12];

    const int N = in_sizes[0] / DIM;   // 50000
    const int E = in_sizes[3];         // 800000

    float* out_h = (float*)d_out;
    float* out_e = out_h + (size_t)N * DIM;

    // workspace layout: Ah|Bh|Dh|Eh (4*N*D f32) | cnt (N i32) | csr (N*CAP i32)
    float* ws = (float*)d_ws;
    float* Ah = ws;
    float* Bh = Ah + (size_t)N * DIM;
    float* Dh = Bh + (size_t)N * DIM;
    float* Eh = Dh + (size_t)N * DIM;
    int* cnt  = (int*)(Eh + (size_t)N * DIM);
    int* csr  = cnt + N;

    hipMemsetAsync(cnt, 0, (size_t)N * sizeof(int), stream);

    const int n4 = (E * DIM) / 4;            // 25.6M float4
    const int gridP = (N + 63) / 64;         // 782
    const int Q = gridP * 16 * 3 * 256;      // proj4's copy share (37.5%)

    proj4_kernel<<<gridP, 256, 0, stream>>>(
        h, norm, WA, bA, WB, bB, WD, bD, WE, bE, Ah, Bh, Dh, Eh, N,
        src, dst, cnt, csr, E,
        (const f4v*)e, (f4v*)out_e);

    aggregate_kernel<<<(N + 3) / 4, 256, 0, stream>>>(
        Ah, Bh, Dh, Eh, norm, cnt, csr, out_h, N,
        (const f4v*)e, (f4v*)out_e, Q, n4);
}